// Round 13
// baseline (3978.179 us; speedup 1.0000x reference)
//
#include <hip/hip_runtime.h>
#include <math.h>

typedef unsigned short u16;
typedef __attribute__((ext_vector_type(4))) unsigned short u16x4;
typedef __attribute__((ext_vector_type(8))) unsigned short u16x8;
typedef __attribute__((ext_vector_type(8))) short s16x8;
typedef __attribute__((ext_vector_type(4))) float f32x4;

#define DEV __device__ __forceinline__

DEV u16 f2bf(float f) {
  unsigned u = __float_as_uint(f);
  u += 0x7fffu + ((u >> 16) & 1u);
  return (u16)(u >> 16);
}
DEV float bf2f(u16 h) { return __uint_as_float(((unsigned)h) << 16); }

DEV void gload_lds16(const u16* g, u16* l) {
  __builtin_amdgcn_global_load_lds(
      (const __attribute__((address_space(1))) unsigned int*)(const void*)g,
      (__attribute__((address_space(3))) unsigned int*)(void*)l, 16, 0, 0);
}

template<int N> DEV void wait_vm() {
  if constexpr (N == 8)      asm volatile("s_waitcnt vmcnt(8)" ::: "memory");
  else if constexpr (N == 6) asm volatile("s_waitcnt vmcnt(6)" ::: "memory");
  else if constexpr (N == 4) asm volatile("s_waitcnt vmcnt(4)" ::: "memory");
  else if constexpr (N == 3) asm volatile("s_waitcnt vmcnt(3)" ::: "memory");
  else                       asm volatile("s_waitcnt vmcnt(0)" ::: "memory");
}

// ---------------- block reduction (blockDim.x == 256) ----------------
DEV float block_sum256(float v, float* sb) {
  #pragma unroll
  for (int o = 32; o > 0; o >>= 1) v += __shfl_down(v, o);
  __syncthreads();
  if ((threadIdx.x & 63) == 0) sb[threadIdx.x >> 6] = v;
  __syncthreads();
  return sb[0] + sb[1] + sb[2] + sb[3];
}

// ---------------- weight transpose + fp32->bf16 ----------------
__global__ __launch_bounds__(256) void wconv_t(const float* __restrict__ in, u16* __restrict__ outp,
                                               int R, int C, size_t ils, size_t ols, float sc) {
  __shared__ float tile[32][33];
  const float* inl = in + (size_t)blockIdx.z * ils;
  u16* outl = outp + (size_t)blockIdx.z * ols;
  int r0 = blockIdx.x * 32, c0 = blockIdx.y * 32;
  int tx = threadIdx.x, ty = threadIdx.y;
  #pragma unroll
  for (int i = ty; i < 32; i += 8)
    tile[i][tx] = inl[(size_t)(r0 + i) * C + (c0 + tx)];
  __syncthreads();
  #pragma unroll
  for (int i = ty; i < 32; i += 8)
    outl[(size_t)(c0 + i) * R + (r0 + tx)] = f2bf(tile[tx][i] * sc);
}

__global__ __launch_bounds__(256) void cvt_bf16_kernel(const float* __restrict__ in, u16* __restrict__ outp, size_t n) {
  size_t i = (size_t)blockIdx.x * blockDim.x + threadIdx.x;
  size_t stride = (size_t)gridDim.x * blockDim.x;
  for (; i < n; i += stride) outp[i] = f2bf(in[i]);
}

// zero-fill 8 u16/thread; block covers 2048 elems; blockIdx.y = slab (stride lstride elems)
__global__ __launch_bounds__(256) void zfill16(u16* __restrict__ p, size_t lstride) {
  size_t o = (size_t)blockIdx.y * lstride + ((size_t)blockIdx.x * 256 + threadIdx.x) * 8;
  *(u16x8*)(p + o) = (u16x8){0, 0, 0, 0, 0, 0, 0, 0};
}

// bias transpose: pb[l][961][16] -> bt[l][16][961]
__global__ __launch_bounds__(256) void bias_tr(const float* __restrict__ pb, float* __restrict__ bt) {
  int l = blockIdx.x;
  for (int idx = threadIdx.x; idx < 961 * 16; idx += 256) {
    int p = idx >> 4, h = idx & 15;
    bt[((size_t)l * 16 + h) * 961 + p] = pb[(size_t)l * 15376 + idx];
  }
}

// =====================================================================
// Deep-pipelined NT GEMM: C[M,N] = A[M,K] * Bt[N,K]  (bf16 in, fp32/bf16 out)
// BM x BN tile, BK=64, 8 waves (WM x WN), DEPTH LDS buffers (2 or 3), counted
// vmcnt: steady-state (DEPTH-1)*LOADS loads in flight; epilogue drains
// (DEPTH-1)L -> ... -> L -> 0 (final-tile staleness race fix, round 3).
// Full 3-bit XOR swizzle: rows are 128 B, so byte bits 7-9 = row bits 0-2.
// Source-permute on stage (o = d ^ ((d>>7)&7)<<4, involution) + matching XOR
// on ds_read (row&7 == rlane&7) -> 2 lanes/bank (free). [round-12: conflicts
// fixed, logits GEMM left top-5]
// KV mode: blocks over cols [N-128, N-64) also scatter into kv[288][64] /
// kvT[64][288] (j = row%256 + 1) and the bx%4==0 blocks write the null row.
// =====================================================================
template<int BM, int BN, int WM, int WN, bool OUTBF, bool KV, int DEPTH>
__global__ __launch_bounds__(512, 2)
void gemm8(const u16* __restrict__ A, const u16* __restrict__ Bt, void* __restrict__ Cout,
           int M, int N, int K, int KS,
           const float* __restrict__ nul, u16* __restrict__ kv, u16* __restrict__ kvT) {
  constexpr int BK = 64;
  constexpr int WROWS = BM / WM, WCOLS = BN / WN;
  constexpr int MR = WROWS / 16, NR = WCOLS / 16;
  constexpr int ABYTES = BM * BK * 2, BBYTES = BN * BK * 2;
  constexpr int TBYTES = ABYTES + BBYTES;
  constexpr int NCHA = ABYTES / 8192, NCHB = BBYTES / 8192;
  constexpr int LOADS = NCHA + NCHB;
  __shared__ char lds[DEPTH * TBYTES];
  const int tid = threadIdx.x;
  const int lane = tid & 63;
  const int wave = tid >> 6;
  const int wr = wave / WN, wc = wave % WN;
  // XCD-contiguous block remap (caller guarantees gridX*gridY % 8 == 0)
  const int gX = gridDim.x;
  const int nwg = gX * gridDim.y;
  const int orig = blockIdx.y * gX + blockIdx.x;
  const int lin = (orig & 7) * (nwg >> 3) + (orig >> 3);
  const int bx = lin % gX, by = lin / gX;
  const size_t m0 = (size_t)bx * BM, n0 = (size_t)by * BN;
  const int k0 = blockIdx.z * KS;
  const size_t ldb = (size_t)K * 2;
  const char* Ab = (const char*)A + m0 * ldb + (size_t)k0 * 2;
  const char* Bb = (const char*)Bt + n0 * ldb + (size_t)k0 * 2;
  const int NT = KS / BK;

  auto stage = [&](int kt, char* buf) {
    const char* ga = Ab + kt * (BK * 2);
    #pragma unroll
    for (int c = 0; c < NCHA; ++c) {
      int d = (tid + c * 512) * 16;
      int o = d ^ (((d >> 7) & 7) << 4);          // inverse 3-bit swizzle (involution)
      gload_lds16((const u16*)(ga + (size_t)(o >> 7) * ldb + (o & 127)), (u16*)(buf + d));
    }
    const char* gb = Bb + kt * (BK * 2);
    #pragma unroll
    for (int c = 0; c < NCHB; ++c) {
      int d = (tid + c * 512) * 16;
      int o = d ^ (((d >> 7) & 7) << 4);
      gload_lds16((const u16*)(gb + (size_t)(o >> 7) * ldb + (o & 127)), (u16*)(buf + ABYTES + d));
    }
  };

  #pragma unroll
  for (int p = 0; p < DEPTH; ++p) stage(p, lds + p * TBYTES);   // NT >= DEPTH for all call sites

  f32x4 acc[MR][NR];
  #pragma unroll
  for (int i = 0; i < MR; ++i)
    #pragma unroll
    for (int j = 0; j < NR; ++j) acc[i][j] = (f32x4){0.f, 0.f, 0.f, 0.f};

  const int rlane = lane & 15;
  const int glane = lane >> 4;
  const int swz = (rlane & 7) << 4;   // row&7 == rlane&7 (row bases are multiples of 16)

  for (int kt = 0; kt < NT; ++kt) {
    char* buf = lds + (kt % DEPTH) * TBYTES;
    const char* At = buf;
    const char* Btl = buf + ABYTES;
    // FIFO vmcnt: waiting until outstanding <= LOADS*rem guarantees stage(kt)
    // (older than all 'rem' later stages) has fully landed. rem is block-uniform.
    {
      int rem = NT - 1 - kt;                 // stages issued after stage(kt)
      if (DEPTH == 2) {
        if (rem >= 1) wait_vm<LOADS>(); else wait_vm<0>();
      } else {
        if (rem >= 2) wait_vm<2 * LOADS>();
        else if (rem == 1) wait_vm<LOADS>();
        else wait_vm<0>();
      }
    }
    asm volatile("s_barrier" ::: "memory");
    s16x8 bfr[NR][2];
    #pragma unroll
    for (int j = 0; j < NR; ++j)
      #pragma unroll
      for (int ks = 0; ks < 2; ++ks) {
        int o = ((wc * WCOLS + j * 16 + rlane) * 128 + ks * 64 + glane * 16) ^ swz;
        bfr[j][ks] = *(const s16x8*)(Btl + o);
      }
    #pragma unroll
    for (int mh = 0; mh < 2; ++mh) {
      s16x8 af[MR / 2][2];
      #pragma unroll
      for (int i = 0; i < MR / 2; ++i)
        #pragma unroll
        for (int ks = 0; ks < 2; ++ks) {
          int row = wr * WROWS + (mh * (MR / 2) + i) * 16 + rlane;
          int o = (row * 128 + ks * 64 + glane * 16) ^ swz;
          af[i][ks] = *(const s16x8*)(At + o);
        }
      __builtin_amdgcn_s_setprio(1);
      #pragma unroll
      for (int i = 0; i < MR / 2; ++i)
        #pragma unroll
        for (int j = 0; j < NR; ++j)
          #pragma unroll
          for (int ks = 0; ks < 2; ++ks)
            acc[mh * (MR / 2) + i][j] = __builtin_amdgcn_mfma_f32_16x16x32_bf16(
                af[i][ks], bfr[j][ks], acc[mh * (MR / 2) + i][j], 0, 0, 0);
      __builtin_amdgcn_s_setprio(0);
    }
    asm volatile("s_waitcnt lgkmcnt(0)\n\ts_barrier" ::: "memory");  // all waves done reading buf
    if (kt + DEPTH < NT) stage(kt + DEPTH, buf);   // overwrites the buffer consumed this iter
  }

  char* Cb = (char*)Cout + (size_t)blockIdx.z * M * (size_t)N * (OUTBF ? 2 : 4);
  #pragma unroll
  for (int i = 0; i < MR; ++i)
    #pragma unroll
    for (int j = 0; j < NR; ++j) {
      size_t row = m0 + wr * WROWS + i * 16 + glane * 4;
      size_t col = n0 + wc * WCOLS + j * 16 + rlane;
      #pragma unroll
      for (int r = 0; r < 4; ++r) {
        size_t off = (row + r) * (size_t)N + col;
        float v = acc[i][j][r];
        if (OUTBF) ((u16*)Cb)[off] = f2bf(v);
        else       ((float*)Cb)[off] = v;
        if (KV) {
          // kv columns live at [N-128, N-64)
          if (col >= (size_t)(N - 128) && col < (size_t)(N - 64)) {
            int d = (int)(col - (N - 128));
            int b = (int)((row + r) >> 8);
            int jj = (int)((row + r) & 255) + 1;
            u16 hv = f2bf(v);
            kv[((size_t)b * 288 + jj) * 64 + d] = hv;
            kvT[((size_t)b * 64 + d) * 288 + jj] = hv;
          }
        }
      }
    }
  if (KV) {
    if ((bx & 3) == 0 && (int)n0 == N - 128 && wave == 0) {
      int b = bx >> 2;
      u16 hv = f2bf(nul[lane]);
      kv[(size_t)b * 288 * 64 + lane] = hv;
      kvT[((size_t)b * 64 + lane) * 288] = hv;
    }
  }
}

// ---------------- LayerNorm over 1024, float4-vectorized ----------------
template<bool OUTBF>
__global__ __launch_bounds__(256) void ln1024(const float* __restrict__ X, const float* __restrict__ g,
                                              float* Of, u16* Ob) {
  __shared__ float sb[4];
  size_t row = blockIdx.x;
  f32x4 v = *(const f32x4*)(X + row * 1024 + threadIdx.x * 4);
  float s = v[0] + v[1] + v[2] + v[3];
  float mu = block_sum256(s, sb) * (1.f / 1024.f);
  float q = 0.f;
  #pragma unroll
  for (int c = 0; c < 4; ++c) { float d = v[c] - mu; q += d * d; }
  float var = block_sum256(q, sb) * (1.f / 1024.f);
  float rs = rsqrtf(var + 1e-5f);
  f32x4 gg = *(const f32x4*)(g + threadIdx.x * 4);
  if (OUTBF) {
    u16x4 o;
    #pragma unroll
    for (int c = 0; c < 4; ++c) o[c] = f2bf((v[c] - mu) * rs * gg[c]);
    *(u16x4*)(Ob + row * 1024 + threadIdx.x * 4) = o;
  } else {
    f32x4 o;
    #pragma unroll
    for (int c = 0; c < 4; ++c) o[c] = (v[c] - mu) * rs * gg[c];
    *(f32x4*)(Of + row * 1024 + threadIdx.x * 4) = o;
  }
}

// ---------------- fused: u = LN(t_bf16)*og + x ; xnew = u ; xn = bf16(LN(u)*g2) ----------------
__global__ __launch_bounds__(256) void lnln_kernel(const u16* __restrict__ T, const float* __restrict__ og,
                                                   const float* __restrict__ X, const float* __restrict__ g2,
                                                   float* __restrict__ Xn, u16* __restrict__ Ob) {
  __shared__ float sb[4];
  size_t row = blockIdx.x;
  size_t o4 = row * 1024 + threadIdx.x * 4;
  u16x4 tv = *(const u16x4*)(T + o4);
  f32x4 v;
  #pragma unroll
  for (int c = 0; c < 4; ++c) v[c] = bf2f(tv[c]);
  float s = v[0] + v[1] + v[2] + v[3];
  float mu = block_sum256(s, sb) * (1.f / 1024.f);
  float q = 0.f;
  #pragma unroll
  for (int c = 0; c < 4; ++c) { float d = v[c] - mu; q += d * d; }
  float var = block_sum256(q, sb) * (1.f / 1024.f);
  float rs = rsqrtf(var + 1e-5f);
  f32x4 ogv = *(const f32x4*)(og + threadIdx.x * 4);
  f32x4 xv  = *(const f32x4*)(X + o4);
  f32x4 u;
  #pragma unroll
  for (int c = 0; c < 4; ++c) u[c] = (v[c] - mu) * rs * ogv[c] + xv[c];
  *(f32x4*)(Xn + o4) = u;
  float s2 = u[0] + u[1] + u[2] + u[3];
  float mu2 = block_sum256(s2, sb) * (1.f / 1024.f);
  float q2 = 0.f;
  #pragma unroll
  for (int c = 0; c < 4; ++c) { float d = u[c] - mu2; q2 += d * d; }
  float var2 = block_sum256(q2, sb) * (1.f / 1024.f);
  float rs2 = rsqrtf(var2 + 1e-5f);
  f32x4 g2v = *(const f32x4*)(g2 + threadIdx.x * 4);
  u16x4 ob;
  #pragma unroll
  for (int c = 0; c < 4; ++c) ob[c] = f2bf((u[c] - mu2) * rs2 * g2v[c]);
  *(u16x4*)(Ob + o4) = ob;
}

// ---------------- fused: v = x + p_bf16 ; xnew = v ; xn = bf16(LN(v)*g) ----------------
__global__ __launch_bounds__(256) void addln_kernel(const float* __restrict__ X, const u16* __restrict__ P0,
                                                    const float* __restrict__ g,
                                                    float* __restrict__ Xn, u16* __restrict__ Ob) {
  __shared__ float sb[4];
  size_t row = blockIdx.x;
  size_t o4 = row * 1024 + threadIdx.x * 4;
  f32x4 a = *(const f32x4*)(X + o4);
  u16x4 pv = *(const u16x4*)(P0 + o4);
  f32x4 v;
  #pragma unroll
  for (int c = 0; c < 4; ++c) v[c] = a[c] + bf2f(pv[c]);
  *(f32x4*)(Xn + o4) = v;
  float s = v[0] + v[1] + v[2] + v[3];
  float mu = block_sum256(s, sb) * (1.f / 1024.f);
  float q = 0.f;
  #pragma unroll
  for (int c = 0; c < 4; ++c) { float d = v[c] - mu; q += d * d; }
  float var = block_sum256(q, sb) * (1.f / 1024.f);
  float rs = rsqrtf(var + 1e-5f);
  f32x4 gg = *(const f32x4*)(g + threadIdx.x * 4);
  u16x4 ob;
  #pragma unroll
  for (int c = 0; c < 4; ++c) ob[c] = f2bf((v[c] - mu) * rs * gg[c]);
  *(u16x4*)(Ob + o4) = ob;
}

// ---------------- gelu (exact) + LayerNorm over 4096, bf16 in/out ----------------
__global__ __launch_bounds__(256) void gelu_ln_bf(const u16* __restrict__ T, const float* __restrict__ g,
                                                  u16* __restrict__ Ob) {
  __shared__ float sb[4];
  size_t row = blockIdx.x;
  size_t o16 = row * 4096 + threadIdx.x * 16;
  u16x8 t0 = *(const u16x8*)(T + o16);
  u16x8 t1 = *(const u16x8*)(T + o16 + 8);
  float v[16];
  #pragma unroll
  for (int c = 0; c < 8; ++c) {
    float a = bf2f(t0[c]);
    v[c] = 0.5f * a * (1.f + erff(a * 0.70710678118654752f));
    float b = bf2f(t1[c]);
    v[c + 8] = 0.5f * b * (1.f + erff(b * 0.70710678118654752f));
  }
  float s = 0.f;
  #pragma unroll
  for (int c = 0; c < 16; ++c) s += v[c];
  float mu = block_sum256(s, sb) * (1.f / 4096.f);
  float q = 0.f;
  #pragma unroll
  for (int c = 0; c < 16; ++c) { float d = v[c] - mu; q += d * d; }
  float var = block_sum256(q, sb) * (1.f / 4096.f);
  float rs = rsqrtf(var + 1e-5f);
  u16x8 o0, o1;
  #pragma unroll
  for (int c = 0; c < 8; ++c) {
    o0[c] = f2bf((v[c] - mu) * rs * g[threadIdx.x * 16 + c]);
    o1[c] = f2bf((v[c + 8] - mu) * rs * g[threadIdx.x * 16 + 8 + c]);
  }
  *(u16x8*)(Ob + o16) = o0;
  *(u16x8*)(Ob + o16 + 8) = o1;
}

// ---------------- embedding + initial LN ----------------
__global__ __launch_bounds__(256) void embed_ln_kernel(const int* __restrict__ ids, const float* __restrict__ tok,
                                                       const float* __restrict__ hpos, const float* __restrict__ wpos,
                                                       const float* __restrict__ start, const float* __restrict__ gamma,
                                                       float* __restrict__ X) {
  __shared__ float sb[4];
  int p = blockIdx.x, b = blockIdx.y;
  float v[4];
  if (p == 0) {
    #pragma unroll
    for (int c = 0; c < 4; ++c) v[c] = start[threadIdx.x + c * 256];
  } else {
    int s = p - 1;
    int id = ids[b * 255 + s];
    #pragma unroll
    for (int c = 0; c < 4; ++c) {
      int col = threadIdx.x + c * 256;
      v[c] = tok[(size_t)id * 1024 + col] + hpos[(s >> 4) * 1024 + col] + wpos[(s & 15) * 1024 + col];
    }
  }
  float s0 = 0.f;
  #pragma unroll
  for (int c = 0; c < 4; ++c) s0 += v[c];
  float mu = block_sum256(s0, sb) * (1.f / 1024.f);
  float q = 0.f;
  #pragma unroll
  for (int c = 0; c < 4; ++c) { float d = v[c] - mu; q += d * d; }
  float var = block_sum256(q, sb) * (1.f / 1024.f);
  float rs = rsqrtf(var + 1e-5f);
  #pragma unroll
  for (int c = 0; c < 4; ++c) {
    int col = threadIdx.x + c * 256;
    X[((size_t)b * 256 + p) * 1024 + col] = (v[c] - mu) * rs * gamma[col];
  }
}

// ---------------- CA kv (batched over layers): src bf16 [2048][sstride] -> per-(l,b) kv/kvT ----------------
__global__ __launch_bounds__(256) void kv_build_ca(const u16* __restrict__ src, int sstride, int scol,
                                                   const float* __restrict__ nul,
                                                   u16* __restrict__ kv, u16* __restrict__ kvT) {
  constexpr int JP = 160, J = 129;
  int b = blockIdx.x, l = blockIdx.y;
  for (int idx = threadIdx.x; idx < JP * 64; idx += 256) {
    int j = idx >> 6, d = idx & 63;
    u16 hv = 0;
    if (j == 0) hv = f2bf(nul[l * 64 + d]);
    else if (j < J) hv = src[(size_t)(b * 128 + j - 1) * sstride + l * scol + d];
    kv[(((size_t)l * 16 + b) * JP + j) * 64 + d] = hv;
    kvT[(((size_t)l * 16 + b) * 64 + d) * JP + j] = hv;
  }
}

// ---------------- MFMA attention (kv rows stride 64; kvT stride = JPT) ----------------
template<int NJT, int KSP, int JPT, bool CAUSAL, bool BIAS>
__global__ __launch_bounds__(256) void attn_mfma(const u16* __restrict__ Q, int QS,
                                                 const u16* __restrict__ kvb, const u16* __restrict__ kvTb,
                                                 const float* __restrict__ bias, u16* __restrict__ O, int J) {
  constexpr int PSTR = KSP * 32 + 16;
  __shared__ __align__(16) u16 Plds[4][16][PSTR];
  const int lane = threadIdx.x & 63, wave = threadIdx.x >> 6;
  const int h = blockIdx.y, b = blockIdx.z;
  const int i0 = blockIdx.x * 64 + wave * 16;
  const int c = lane & 15, g = lane >> 4;
  const float* biasrow = BIAS ? (bias + (size_t)h * 961) : nullptr;

  s16x8 aq[2];
  #pragma unroll
  for (int ks = 0; ks < 2; ++ks)
    aq[ks] = *(const s16x8*)(Q + (size_t)(b * 256 + i0 + c) * QS + h * 64 + ks * 32 + g * 8);

  f32x4 acc[NJT];
  #pragma unroll
  for (int jt = 0; jt < NJT; ++jt) acc[jt] = (f32x4){0.f, 0.f, 0.f, 0.f};

  const u16* kvB = kvb + (size_t)b * JPT * 64;
  __builtin_amdgcn_s_setprio(1);
  #pragma unroll
  for (int ks = 0; ks < 2; ++ks) {
    #pragma unroll
    for (int jt = 0; jt < NJT; ++jt) {
      s16x8 bf = *(const s16x8*)(kvB + (size_t)(jt * 16 + c) * 64 + ks * 32 + g * 8);
      acc[jt] = __builtin_amdgcn_mfma_f32_16x16x32_bf16(aq[ks], bf, acc[jt], 0, 0, 0);
    }
  }
  __builtin_amdgcn_s_setprio(0);

  const float NEGINF = -__builtin_inff();
  #pragma unroll
  for (int r = 0; r < 4; ++r) {
    const int i = i0 + g * 4 + r;
    float mx = NEGINF;
    #pragma unroll
    for (int jt = 0; jt < NJT; ++jt) {
      int j = jt * 16 + c;
      float s = acc[jt][r];
      if (j >= J) s = NEGINF;
      else {
        if (BIAS && j >= 1) {
          int t = j - 1;
          int idx = ((i >> 4) - (t >> 4) + 15) * 31 + ((i & 15) - (t & 15) + 15);
          s += biasrow[idx];
        }
        if (CAUSAL && j > i + 1) s = NEGINF;
      }
      acc[jt][r] = s;
      mx = fmaxf(mx, s);
    }
    #pragma unroll
    for (int o = 1; o < 16; o <<= 1) mx = fmaxf(mx, __shfl_xor(mx, o));
    float sum = 0.f;
    #pragma unroll
    for (int jt = 0; jt < NJT; ++jt) {
      float p = __expf(acc[jt][r] - mx);
      acc[jt][r] = p;
      sum += p;
    }
    #pragma unroll
    for (int o = 1; o < 16; o <<= 1) sum += __shfl_xor(sum, o);
    float inv = 1.f / sum;
    #pragma unroll
    for (int jt = 0; jt < NJT; ++jt)
      Plds[wave][g * 4 + r][jt * 16 + c] = f2bf(acc[jt][r] * inv);
  }
  #pragma unroll
  for (int z = 0; z < 4; ++z)
    Plds[wave][c][NJT * 16 + g * 4 + z] = 0;

  s16x8 pa[KSP];
  #pragma unroll
  for (int ks = 0; ks < KSP; ++ks)
    pa[ks] = *(const s16x8*)(&Plds[wave][c][ks * 32 + g * 8]);
  const u16* kvT = kvTb + (size_t)b * 64 * JPT;
  #pragma unroll
  for (int nt = 0; nt < 4; ++nt) {
    f32x4 ov = (f32x4){0.f, 0.f, 0.f, 0.f};
    __builtin_amdgcn_s_setprio(1);
    #pragma unroll
    for (int ks = 0; ks < KSP; ++ks) {
      s16x8 bv = *(const s16x8*)(kvT + (size_t)(nt * 16 + c) * JPT + ks * 32 + g * 8);
      ov = __builtin_amdgcn_mfma_f32_16x16x32_bf16(pa[ks], bv, ov, 0, 0, 0);
    }
    __builtin_amdgcn_s_setprio(0);
    #pragma unroll
    for (int r = 0; r < 4; ++r)
      O[(size_t)(b * 256 + i0 + g * 4 + r) * 1024 + h * 64 + nt * 16 + c] = f2bf(ov[r]);
  }
}

// =====================================================================
extern "C" void kernel_launch(void* const* d_in, const int* in_sizes, int n_in,
                              void* d_out, int out_size, void* d_ws, size_t ws_size,
                              hipStream_t stream) {
  const int*   ids     = (const int*)  d_in[0];
  const float* text    = (const float*)d_in[1];
  const float* tok     = (const float*)d_in[3];
  const float* hpos    = (const float*)d_in[4];
  const float* wpos    = (const float*)d_in[5];
  const float* start   = (const float*)d_in[6];
  const float* initg   = (const float*)d_in[7];
  const float* sa_g    = (const float*)d_in[8];
  const float* sa_Wq   = (const float*)d_in[9];
  const float* sa_nul  = (const float*)d_in[10];
  const float* sa_Wkv  = (const float*)d_in[11];
  const float* sa_Wout = (const float*)d_in[12];
  const float* sa_og   = (const float*)d_in[13];
  const float* sa_pb   = (const float*)d_in[14];
  const float* ca_g    = (const float*)d_in[15];
  const float* ca_Wq   = (const float*)d_in[16];
  const float* ca_nul  = (const float*)d_in[17];
  const float* ca_Wkv  = (const float*)d_in[18];
  const float* ca_Wout = (const float*)d_in[19];
  const float* ca_og   = (const float*)d_in[20];
  const float* ff_g1   = (const float*)d_in[21];
  const float* ff_W1   = (const float*)d_in[22];
  const float* ff_g2   = (const float*)d_in[23];
  const float* ff_W2   = (const float*)d_in[24];
  const float* fing    = (const float*)d_in[25];
  float* out = (float*)d_out;

  char* base = (char*)d_ws;
  size_t off = 0;
  auto carve = [&](size_t bytes) -> char* {
    off = (off + 255) & ~(size_t)255;
    char* p = base + off;
    off += bytes;
    return p;
  };
  float* x       = (float*)carve(4096ull * 1024 * 4);
  float* t       = (float*)carve(4096ull * 4096 * 4);   // aliased bf16 for all GEMM outs
  u16*   xn      = (u16*)  carve(4096ull * 1024 * 2);
  u16*   qkv     = (u16*)  carve(4096ull * 1152 * 2);
  u16*   qb      = (u16*)  carve(4096ull * 1024 * 2);
  u16*   ao      = (u16*)  carve(4096ull * 1024 * 2);
  u16*   hb      = (u16*)  carve(4096ull * 4096 * 2);
  u16*   kvbuf   = (u16*)  carve(16ull * 288 * 64 * 2);
  u16*   kvTbuf  = (u16*)  carve(16ull * 64 * 288 * 2);
  u16*   cakv    = (u16*)  carve(12ull * 16 * 160 * 64 * 2);
  u16*   cakvT   = (u16*)  carve(12ull * 16 * 64 * 160 * 2);
  u16*   catmp   = (u16*)  carve(2048ull * 768 * 2);
  u16*   cakvw   = (u16*)  carve(12ull * 64 * 768 * 2);
  u16*   cakvw1  = (u16*)  carve(128ull * 768 * 2);
  u16*   catmp1  = (u16*)  carve(2048ull * 128 * 2);
  u16*   textbf  = (u16*)  carve(2048ull * 768 * 2);
  u16*   tokbf   = (u16*)  carve(8192ull * 1024 * 2);
  float* biast   = (float*)carve(12ull * 16 * 961 * 4);
  u16*   tbb     = (u16*)t;   // bf16 view of t

  const size_t O_WQKV = 0;                    // [1152][1024]
  const size_t O_WOUT = 1179648;
  const size_t O_CWQ  = 2228224;
  const size_t O_CWOUT= 3276800;
  const size_t O_W1   = 4325376;
  const size_t O_W2   = 8519680;
  const size_t LAYER_E = 12713984ull;
  size_t off_now = (off + 255) & ~(size_t)255;
  bool allw = (off_now + 12 * LAYER_E * 2) <= ws_size;
  u16* wbase = (u16*)carve((allw ? 12 : 1) * LAYER_E * 2);

  dim3 tb8(32, 8);
  auto conv = [&](const float* in, u16* op, int R, int C, int L, float sc) {
    wconv_t<<<dim3(R / 32, C / 32, L), tb8, 0, stream>>>(in, op, R, C, (size_t)R * C, LAYER_E, sc);
  };
  if (allw) {
    conv(sa_Wq,   wbase + O_WQKV,            1024, 1024, 12, 0.125f);
    conv(sa_Wkv,  wbase + O_WQKV + 1048576,  1024, 64,   12, 1.f);
    zfill16<<<dim3(32, 12), 256, 0, stream>>>(wbase + O_WQKV + 1114112, LAYER_E);
    conv(sa_Wout, wbase + O_WOUT,  1024, 1024, 12, 1.f);
    conv(ca_Wq,   wbase + O_CWQ,   1024, 1024, 12, 0.125f);
    conv(ca_Wout, wbase + O_CWOUT, 1024, 1024, 12, 1.f);
    conv(ff_W1,   wbase + O_W1,    1024, 4096, 12, 1.f);
    conv(ff_W2,   wbase + O_W2,    4096, 1024, 12, 1.f);
    wconv_t<<<dim3(24, 2, 12), tb8, 0, stream>>>(ca_Wkv, cakvw, 768, 64, 49152, 49152, 1.f);
  }
  bias_tr<<<12, 256, 0, stream>>>(sa_pb, biast);
  // zero SA kv buffers once: pads (j>=257) stay zero; live region rewritten each layer
  zfill16<<<dim3(144, 1), 256, 0, stream>>>(kvbuf, 0);
  zfill16<<<dim3(144, 1), 256, 0, stream>>>(kvTbuf, 0);
  cvt_bf16_kernel<<<2048, 256, 0, stream>>>(tok, tokbf, 8192ull * 1024);
  cvt_bf16_kernel<<<1024, 256, 0, stream>>>(text, textbf, 2048ull * 768);
  if (allw) {
    gemm8<128, 128, 2, 4, true, false, 2><<<dim3(16, 6, 1), 512, 0, stream>>>(textbf, cakvw, catmp, 2048, 768, 768, 768, nullptr, nullptr, nullptr);
    kv_build_ca<<<dim3(16, 12), 256, 0, stream>>>(catmp, 768, 64, ca_nul, cakv, cakvT);
  }
  embed_ln_kernel<<<dim3(256, 16), 256, 0, stream>>>(ids, tok, hpos, wpos, start, initg, x);
  ln1024<true><<<4096, 256, 0, stream>>>(x, sa_g, nullptr, xn);

  for (int l = 0; l < 12; ++l) {
    u16* W = allw ? (wbase + (size_t)l * LAYER_E) : wbase;
    if (!allw) {
      conv(sa_Wq   + (size_t)l * 1048576, W + O_WQKV,           1024, 1024, 1, 0.125f);
      conv(sa_Wkv  + (size_t)l * 65536,   W + O_WQKV + 1048576, 1024, 64,   1, 1.f);
      zfill16<<<dim3(32, 1), 256, 0, stream>>>(W + O_WQKV + 1114112, 0);
      conv(sa_Wout + (size_t)l * 1048576, W + O_WOUT,  1024, 1024, 1, 1.f);
      conv(ca_Wq   + (size_t)l * 1048576, W + O_CWQ,   1024, 1024, 1, 0.125f);
      conv(ca_Wout + (size_t)l * 1048576, W + O_CWOUT, 1024, 1024, 1, 1.f);
      conv(ff_W1   + (size_t)l * 4194304, W + O_W1,    1024, 4096, 1, 1.f);
      conv(ff_W2   + (size_t)l * 4194304, W + O_W2,    4096, 1024, 1, 1.f);
      wconv_t<<<dim3(24, 2, 1), tb8, 0, stream>>>(ca_Wkv + (size_t)l * 49152, cakvw1, 768, 64, 0, 0, 1.f);
      zfill16<<<dim3(24, 1), 256, 0, stream>>>(cakvw1 + 64 * 768, 0);
      gemm8<128, 128, 2, 4, true, false, 2><<<dim3(16, 1, 1), 512, 0, stream>>>(textbf, cakvw1, catmp1, 2048, 128, 768, 768, nullptr, nullptr, nullptr);
      kv_build_ca<<<dim3(16, 1), 256, 0, stream>>>(catmp1, 128, 0, ca_nul + l * 64,
                                                   cakv + (size_t)l * 16 * 160 * 64,
                                                   cakvT + (size_t)l * 16 * 64 * 160);
    }
    // ---- self-attention block (xn holds LN(x)*sa_g[l]) ----
    gemm8<64, 128, 2, 4, true, true, 3><<<dim3(64, 9, 1), 512, 0, stream>>>(xn, W + O_WQKV, qkv, 4096, 1152, 1024, 1024,
                                                                            sa_nul + l * 64, kvbuf, kvTbuf);
    attn_mfma<17, 9, 288, true, true><<<dim3(4, 16, 16), 256, 0, stream>>>(qkv, 1152, kvbuf, kvTbuf,
                                                                           biast + (size_t)l * 16 * 961, ao, 257);
    gemm8<64, 128, 2, 4, true, false, 3><<<dim3(64, 8, 1), 512, 0, stream>>>(ao, W + O_WOUT, tbb, 4096, 1024, 1024, 1024, nullptr, nullptr, nullptr);
    lnln_kernel<<<4096, 256, 0, stream>>>(tbb, sa_og + l * 1024, x, ca_g + l * 1024, x, xn);
    // ---- cross-attention block ----
    gemm8<64, 128, 2, 4, true, false, 3><<<dim3(64, 8, 1), 512, 0, stream>>>(xn, W + O_CWQ, qb, 4096, 1024, 1024, 1024, nullptr, nullptr, nullptr);
    attn_mfma<9, 5, 160, false, false><<<dim3(4, 16, 16), 256, 0, stream>>>(qb, 1024,
                                                                            cakv + (size_t)l * 16 * 160 * 64,
                                                                            cakvT + (size_t)l * 16 * 64 * 160,
                                                                            nullptr, ao, 129);
    gemm8<64, 128, 2, 4, true, false, 3><<<dim3(64, 8, 1), 512, 0, stream>>>(ao, W + O_CWOUT, tbb, 4096, 1024, 1024, 1024, nullptr, nullptr, nullptr);
    lnln_kernel<<<4096, 256, 0, stream>>>(tbb, ca_og + l * 1024, x, ff_g1 + l * 1024, x, xn);
    // ---- feed-forward block (all bf16 intermediates) ----
    gemm8<256, 256, 2, 4, true, false, 2><<<dim3(16, 16, 1), 512, 0, stream>>>(xn, W + O_W1, tbb, 4096, 4096, 1024, 1024, nullptr, nullptr, nullptr);
    gelu_ln_bf<<<4096, 256, 0, stream>>>(tbb, ff_g2 + (size_t)l * 4096, hb);
    gemm8<64, 128, 2, 4, true, false, 3><<<dim3(64, 8, 1), 512, 0, stream>>>(hb, W + O_W2, tbb, 4096, 1024, 4096, 4096, nullptr, nullptr, nullptr);
    addln_kernel<<<4096, 256, 0, stream>>>(x, tbb, (l < 11 ? sa_g + (l + 1) * 1024 : fing), x, xn);
  }
  // ---- logits (xn = final LN) ----
  gemm8<256, 256, 2, 4, false, false, 2><<<dim3(16, 32, 1), 512, 0, stream>>>(xn, tokbf, out, 4096, 8192, 1024, 1024, nullptr, nullptr, nullptr);
}

// Round 14
// 3885.331 us; speedup vs baseline: 1.0239x; 1.0239x over previous
//
#include <hip/hip_runtime.h>
#include <math.h>

typedef unsigned short u16;
typedef __attribute__((ext_vector_type(4))) unsigned short u16x4;
typedef __attribute__((ext_vector_type(8))) unsigned short u16x8;
typedef __attribute__((ext_vector_type(8))) short s16x8;
typedef __attribute__((ext_vector_type(4))) float f32x4;

#define DEV __device__ __forceinline__

DEV u16 f2bf(float f) {
  unsigned u = __float_as_uint(f);
  u += 0x7fffu + ((u >> 16) & 1u);
  return (u16)(u >> 16);
}
DEV float bf2f(u16 h) { return __uint_as_float(((unsigned)h) << 16); }

DEV void gload_lds16(const u16* g, u16* l) {
  __builtin_amdgcn_global_load_lds(
      (const __attribute__((address_space(1))) unsigned int*)(const void*)g,
      (__attribute__((address_space(3))) unsigned int*)(void*)l, 16, 0, 0);
}

template<int N> DEV void wait_vm() {
  if constexpr (N == 8)      asm volatile("s_waitcnt vmcnt(8)" ::: "memory");
  else if constexpr (N == 6) asm volatile("s_waitcnt vmcnt(6)" ::: "memory");
  else if constexpr (N == 4) asm volatile("s_waitcnt vmcnt(4)" ::: "memory");
  else if constexpr (N == 3) asm volatile("s_waitcnt vmcnt(3)" ::: "memory");
  else                       asm volatile("s_waitcnt vmcnt(0)" ::: "memory");
}

// ---------------- block reduction (blockDim.x == 256) ----------------
DEV float block_sum256(float v, float* sb) {
  #pragma unroll
  for (int o = 32; o > 0; o >>= 1) v += __shfl_down(v, o);
  __syncthreads();
  if ((threadIdx.x & 63) == 0) sb[threadIdx.x >> 6] = v;
  __syncthreads();
  return sb[0] + sb[1] + sb[2] + sb[3];
}

// ---------------- weight transpose + fp32->bf16 ----------------
__global__ __launch_bounds__(256) void wconv_t(const float* __restrict__ in, u16* __restrict__ outp,
                                               int R, int C, size_t ils, size_t ols, float sc) {
  __shared__ float tile[32][33];
  const float* inl = in + (size_t)blockIdx.z * ils;
  u16* outl = outp + (size_t)blockIdx.z * ols;
  int r0 = blockIdx.x * 32, c0 = blockIdx.y * 32;
  int tx = threadIdx.x, ty = threadIdx.y;
  #pragma unroll
  for (int i = ty; i < 32; i += 8)
    tile[i][tx] = inl[(size_t)(r0 + i) * C + (c0 + tx)];
  __syncthreads();
  #pragma unroll
  for (int i = ty; i < 32; i += 8)
    outl[(size_t)(c0 + i) * R + (r0 + tx)] = f2bf(tile[tx][i] * sc);
}

__global__ __launch_bounds__(256) void cvt_bf16_kernel(const float* __restrict__ in, u16* __restrict__ outp, size_t n) {
  size_t i = (size_t)blockIdx.x * blockDim.x + threadIdx.x;
  size_t stride = (size_t)gridDim.x * blockDim.x;
  for (; i < n; i += stride) outp[i] = f2bf(in[i]);
}

// zero-fill 8 u16/thread; block covers 2048 elems; blockIdx.y = slab (stride lstride elems)
__global__ __launch_bounds__(256) void zfill16(u16* __restrict__ p, size_t lstride) {
  size_t o = (size_t)blockIdx.y * lstride + ((size_t)blockIdx.x * 256 + threadIdx.x) * 8;
  *(u16x8*)(p + o) = (u16x8){0, 0, 0, 0, 0, 0, 0, 0};
}

// bias transpose: pb[l][961][16] -> bt[l][16][961]
__global__ __launch_bounds__(256) void bias_tr(const float* __restrict__ pb, float* __restrict__ bt) {
  int l = blockIdx.x;
  for (int idx = threadIdx.x; idx < 961 * 16; idx += 256) {
    int p = idx >> 4, h = idx & 15;
    bt[((size_t)l * 16 + h) * 961 + p] = pb[(size_t)l * 15376 + idx];
  }
}

// =====================================================================
// Deep-pipelined NT GEMM: C[M,N] = A[M,K] * Bt[N,K]  (bf16 in, fp32/bf16 out)
// BM x BN tile, BK=64, 8 waves (WM x WN), 2 LDS buffers, counted vmcnt
// (drained to 0 on the final tile).
// Full 3-bit XOR swizzle (round 12): source-permute on stage + matching XOR
// on ds_read -> 2 lanes/bank (free).
// XCD mapping (round 14): PANEL-CONTIGUOUS — xcd = orig&7 owns bx in
// {xcd, xcd+8, ...}: each XCD's L2 keeps 1-8 A-panels resident and streams
// each B col-panel once. [round-11 counters: old scatter mapping caused
// 245 MB HBM fetch on the logits GEMM vs ~24 MB ideal]
// Requires gridDim.x % 8 == 0 (all call sites: gX in {16, 64}).
// KV mode: blocks over cols [N-128, N-64) also scatter into kv[288][64] /
// kvT[64][288] (j = row%256 + 1) and the bx%4==0 blocks write the null row.
// =====================================================================
template<int BM, int BN, int WM, int WN, bool OUTBF, bool KV>
__global__ __launch_bounds__(512, 2)
void gemm8(const u16* __restrict__ A, const u16* __restrict__ Bt, void* __restrict__ Cout,
           int M, int N, int K, int KS,
           const float* __restrict__ nul, u16* __restrict__ kv, u16* __restrict__ kvT) {
  constexpr int BK = 64;
  constexpr int WROWS = BM / WM, WCOLS = BN / WN;
  constexpr int MR = WROWS / 16, NR = WCOLS / 16;
  constexpr int ABYTES = BM * BK * 2, BBYTES = BN * BK * 2;
  constexpr int TBYTES = ABYTES + BBYTES;
  constexpr int NCHA = ABYTES / 8192, NCHB = BBYTES / 8192;
  constexpr int LOADS = NCHA + NCHB;
  __shared__ char lds[2 * TBYTES];
  const int tid = threadIdx.x;
  const int lane = tid & 63;
  const int wave = tid >> 6;
  const int wr = wave / WN, wc = wave % WN;
  // Panel-contiguous XCD remap (bijective; gX % 8 == 0 at every call site):
  //   xcd = orig&7, idx = orig>>3, bx = xcd + 8*(idx % (gX/8)), by = idx/(gX/8)
  const int gX = gridDim.x;
  const int orig = blockIdx.y * gX + blockIdx.x;
  const int gx8 = gX >> 3;
  const int xcd = orig & 7;
  const int idx = orig >> 3;
  const int bx = xcd + 8 * (idx % gx8);
  const int by = idx / gx8;
  const size_t m0 = (size_t)bx * BM, n0 = (size_t)by * BN;
  const int k0 = blockIdx.z * KS;
  const size_t ldb = (size_t)K * 2;
  const char* Ab = (const char*)A + m0 * ldb + (size_t)k0 * 2;
  const char* Bb = (const char*)Bt + n0 * ldb + (size_t)k0 * 2;
  const int NT = KS / BK;

  auto stage = [&](int kt, char* buf) {
    const char* ga = Ab + kt * (BK * 2);
    #pragma unroll
    for (int c = 0; c < NCHA; ++c) {
      int d = (tid + c * 512) * 16;
      int o = d ^ (((d >> 7) & 7) << 4);          // inverse 3-bit swizzle (involution)
      gload_lds16((const u16*)(ga + (size_t)(o >> 7) * ldb + (o & 127)), (u16*)(buf + d));
    }
    const char* gb = Bb + kt * (BK * 2);
    #pragma unroll
    for (int c = 0; c < NCHB; ++c) {
      int d = (tid + c * 512) * 16;
      int o = d ^ (((d >> 7) & 7) << 4);
      gload_lds16((const u16*)(gb + (size_t)(o >> 7) * ldb + (o & 127)), (u16*)(buf + ABYTES + d));
    }
  };

  stage(0, lds);
  stage(1, lds + TBYTES);

  f32x4 acc[MR][NR];
  #pragma unroll
  for (int i = 0; i < MR; ++i)
    #pragma unroll
    for (int j = 0; j < NR; ++j) acc[i][j] = (f32x4){0.f, 0.f, 0.f, 0.f};

  const int rlane = lane & 15;
  const int glane = lane >> 4;
  const int swz = (rlane & 7) << 4;   // row&7 == rlane&7 (row bases are multiples of 16)

  for (int kt = 0; kt < NT; ++kt) {
    char* buf = lds + (kt & 1) * TBYTES;
    const char* At = buf;
    const char* Btl = buf + ABYTES;
    // Steady state: stage(kt+1)'s LOADS in flight. Final tile: drain to 0
    // (round-3 staleness race fix). Branch is block-uniform.
    if (kt + 1 < NT) wait_vm<LOADS>(); else wait_vm<0>();
    asm volatile("s_barrier" ::: "memory");
    s16x8 bfr[NR][2];
    #pragma unroll
    for (int j = 0; j < NR; ++j)
      #pragma unroll
      for (int ks = 0; ks < 2; ++ks) {
        int o = ((wc * WCOLS + j * 16 + rlane) * 128 + ks * 64 + glane * 16) ^ swz;
        bfr[j][ks] = *(const s16x8*)(Btl + o);
      }
    #pragma unroll
    for (int mh = 0; mh < 2; ++mh) {
      s16x8 af[MR / 2][2];
      #pragma unroll
      for (int i = 0; i < MR / 2; ++i)
        #pragma unroll
        for (int ks = 0; ks < 2; ++ks) {
          int row = wr * WROWS + (mh * (MR / 2) + i) * 16 + rlane;
          int o = (row * 128 + ks * 64 + glane * 16) ^ swz;
          af[i][ks] = *(const s16x8*)(At + o);
        }
      __builtin_amdgcn_s_setprio(1);
      #pragma unroll
      for (int i = 0; i < MR / 2; ++i)
        #pragma unroll
        for (int j = 0; j < NR; ++j)
          #pragma unroll
          for (int ks = 0; ks < 2; ++ks)
            acc[mh * (MR / 2) + i][j] = __builtin_amdgcn_mfma_f32_16x16x32_bf16(
                af[i][ks], bfr[j][ks], acc[mh * (MR / 2) + i][j], 0, 0, 0);
      __builtin_amdgcn_s_setprio(0);
    }
    asm volatile("s_waitcnt lgkmcnt(0)\n\ts_barrier" ::: "memory");  // all waves done reading buf
    if (kt + 2 < NT) stage(kt + 2, buf);
  }

  char* Cb = (char*)Cout + (size_t)blockIdx.z * M * (size_t)N * (OUTBF ? 2 : 4);
  #pragma unroll
  for (int i = 0; i < MR; ++i)
    #pragma unroll
    for (int j = 0; j < NR; ++j) {
      size_t row = m0 + wr * WROWS + i * 16 + glane * 4;
      size_t col = n0 + wc * WCOLS + j * 16 + rlane;
      #pragma unroll
      for (int r = 0; r < 4; ++r) {
        size_t off = (row + r) * (size_t)N + col;
        float v = acc[i][j][r];
        if (OUTBF) ((u16*)Cb)[off] = f2bf(v);
        else       ((float*)Cb)[off] = v;
        if (KV) {
          // kv columns live at [N-128, N-64)
          if (col >= (size_t)(N - 128) && col < (size_t)(N - 64)) {
            int d = (int)(col - (N - 128));
            int b = (int)((row + r) >> 8);
            int jj = (int)((row + r) & 255) + 1;
            u16 hv = f2bf(v);
            kv[((size_t)b * 288 + jj) * 64 + d] = hv;
            kvT[((size_t)b * 64 + d) * 288 + jj] = hv;
          }
        }
      }
    }
  if (KV) {
    if ((bx & 3) == 0 && (int)n0 == N - 128 && wave == 0) {
      int b = bx >> 2;
      u16 hv = f2bf(nul[lane]);
      kv[(size_t)b * 288 * 64 + lane] = hv;
      kvT[((size_t)b * 64 + lane) * 288] = hv;
    }
  }
}

// ---------------- LayerNorm over 1024, float4-vectorized ----------------
template<bool OUTBF>
__global__ __launch_bounds__(256) void ln1024(const float* __restrict__ X, const float* __restrict__ g,
                                              float* Of, u16* Ob) {
  __shared__ float sb[4];
  size_t row = blockIdx.x;
  f32x4 v = *(const f32x4*)(X + row * 1024 + threadIdx.x * 4);
  float s = v[0] + v[1] + v[2] + v[3];
  float mu = block_sum256(s, sb) * (1.f / 1024.f);
  float q = 0.f;
  #pragma unroll
  for (int c = 0; c < 4; ++c) { float d = v[c] - mu; q += d * d; }
  float var = block_sum256(q, sb) * (1.f / 1024.f);
  float rs = rsqrtf(var + 1e-5f);
  f32x4 gg = *(const f32x4*)(g + threadIdx.x * 4);
  if (OUTBF) {
    u16x4 o;
    #pragma unroll
    for (int c = 0; c < 4; ++c) o[c] = f2bf((v[c] - mu) * rs * gg[c]);
    *(u16x4*)(Ob + row * 1024 + threadIdx.x * 4) = o;
  } else {
    f32x4 o;
    #pragma unroll
    for (int c = 0; c < 4; ++c) o[c] = (v[c] - mu) * rs * gg[c];
    *(f32x4*)(Of + row * 1024 + threadIdx.x * 4) = o;
  }
}

// ---------------- fused: u = LN(t_bf16)*og + x ; xnew = u ; xn = bf16(LN(u)*g2) ----------------
__global__ __launch_bounds__(256) void lnln_kernel(const u16* __restrict__ T, const float* __restrict__ og,
                                                   const float* __restrict__ X, const float* __restrict__ g2,
                                                   float* __restrict__ Xn, u16* __restrict__ Ob) {
  __shared__ float sb[4];
  size_t row = blockIdx.x;
  size_t o4 = row * 1024 + threadIdx.x * 4;
  u16x4 tv = *(const u16x4*)(T + o4);
  f32x4 v;
  #pragma unroll
  for (int c = 0; c < 4; ++c) v[c] = bf2f(tv[c]);
  float s = v[0] + v[1] + v[2] + v[3];
  float mu = block_sum256(s, sb) * (1.f / 1024.f);
  float q = 0.f;
  #pragma unroll
  for (int c = 0; c < 4; ++c) { float d = v[c] - mu; q += d * d; }
  float var = block_sum256(q, sb) * (1.f / 1024.f);
  float rs = rsqrtf(var + 1e-5f);
  f32x4 ogv = *(const f32x4*)(og + threadIdx.x * 4);
  f32x4 xv  = *(const f32x4*)(X + o4);
  f32x4 u;
  #pragma unroll
  for (int c = 0; c < 4; ++c) u[c] = (v[c] - mu) * rs * ogv[c] + xv[c];
  *(f32x4*)(Xn + o4) = u;
  float s2 = u[0] + u[1] + u[2] + u[3];
  float mu2 = block_sum256(s2, sb) * (1.f / 1024.f);
  float q2 = 0.f;
  #pragma unroll
  for (int c = 0; c < 4; ++c) { float d = u[c] - mu2; q2 += d * d; }
  float var2 = block_sum256(q2, sb) * (1.f / 1024.f);
  float rs2 = rsqrtf(var2 + 1e-5f);
  f32x4 g2v = *(const f32x4*)(g2 + threadIdx.x * 4);
  u16x4 ob;
  #pragma unroll
  for (int c = 0; c < 4; ++c) ob[c] = f2bf((u[c] - mu2) * rs2 * g2v[c]);
  *(u16x4*)(Ob + o4) = ob;
}

// ---------------- fused: v = x + p_bf16 ; xnew = v ; xn = bf16(LN(v)*g) ----------------
__global__ __launch_bounds__(256) void addln_kernel(const float* __restrict__ X, const u16* __restrict__ P0,
                                                    const float* __restrict__ g,
                                                    float* __restrict__ Xn, u16* __restrict__ Ob) {
  __shared__ float sb[4];
  size_t row = blockIdx.x;
  size_t o4 = row * 1024 + threadIdx.x * 4;
  f32x4 a = *(const f32x4*)(X + o4);
  u16x4 pv = *(const u16x4*)(P0 + o4);
  f32x4 v;
  #pragma unroll
  for (int c = 0; c < 4; ++c) v[c] = a[c] + bf2f(pv[c]);
  *(f32x4*)(Xn + o4) = v;
  float s = v[0] + v[1] + v[2] + v[3];
  float mu = block_sum256(s, sb) * (1.f / 1024.f);
  float q = 0.f;
  #pragma unroll
  for (int c = 0; c < 4; ++c) { float d = v[c] - mu; q += d * d; }
  float var = block_sum256(q, sb) * (1.f / 1024.f);
  float rs = rsqrtf(var + 1e-5f);
  f32x4 gg = *(const f32x4*)(g + threadIdx.x * 4);
  u16x4 ob;
  #pragma unroll
  for (int c = 0; c < 4; ++c) ob[c] = f2bf((v[c] - mu) * rs * gg[c]);
  *(u16x4*)(Ob + o4) = ob;
}

// ---------------- gelu (exact) + LayerNorm over 4096, bf16 in/out ----------------
__global__ __launch_bounds__(256) void gelu_ln_bf(const u16* __restrict__ T, const float* __restrict__ g,
                                                  u16* __restrict__ Ob) {
  __shared__ float sb[4];
  size_t row = blockIdx.x;
  size_t o16 = row * 4096 + threadIdx.x * 16;
  u16x8 t0 = *(const u16x8*)(T + o16);
  u16x8 t1 = *(const u16x8*)(T + o16 + 8);
  float v[16];
  #pragma unroll
  for (int c = 0; c < 8; ++c) {
    float a = bf2f(t0[c]);
    v[c] = 0.5f * a * (1.f + erff(a * 0.70710678118654752f));
    float b = bf2f(t1[c]);
    v[c + 8] = 0.5f * b * (1.f + erff(b * 0.70710678118654752f));
  }
  float s = 0.f;
  #pragma unroll
  for (int c = 0; c < 16; ++c) s += v[c];
  float mu = block_sum256(s, sb) * (1.f / 4096.f);
  float q = 0.f;
  #pragma unroll
  for (int c = 0; c < 16; ++c) { float d = v[c] - mu; q += d * d; }
  float var = block_sum256(q, sb) * (1.f / 4096.f);
  float rs = rsqrtf(var + 1e-5f);
  u16x8 o0, o1;
  #pragma unroll
  for (int c = 0; c < 8; ++c) {
    o0[c] = f2bf((v[c] - mu) * rs * g[threadIdx.x * 16 + c]);
    o1[c] = f2bf((v[c + 8] - mu) * rs * g[threadIdx.x * 16 + 8 + c]);
  }
  *(u16x8*)(Ob + o16) = o0;
  *(u16x8*)(Ob + o16 + 8) = o1;
}

// ---------------- embedding + initial LN ----------------
__global__ __launch_bounds__(256) void embed_ln_kernel(const int* __restrict__ ids, const float* __restrict__ tok,
                                                       const float* __restrict__ hpos, const float* __restrict__ wpos,
                                                       const float* __restrict__ start, const float* __restrict__ gamma,
                                                       float* __restrict__ X) {
  __shared__ float sb[4];
  int p = blockIdx.x, b = blockIdx.y;
  float v[4];
  if (p == 0) {
    #pragma unroll
    for (int c = 0; c < 4; ++c) v[c] = start[threadIdx.x + c * 256];
  } else {
    int s = p - 1;
    int id = ids[b * 255 + s];
    #pragma unroll
    for (int c = 0; c < 4; ++c) {
      int col = threadIdx.x + c * 256;
      v[c] = tok[(size_t)id * 1024 + col] + hpos[(s >> 4) * 1024 + col] + wpos[(s & 15) * 1024 + col];
    }
  }
  float s0 = 0.f;
  #pragma unroll
  for (int c = 0; c < 4; ++c) s0 += v[c];
  float mu = block_sum256(s0, sb) * (1.f / 1024.f);
  float q = 0.f;
  #pragma unroll
  for (int c = 0; c < 4; ++c) { float d = v[c] - mu; q += d * d; }
  float var = block_sum256(q, sb) * (1.f / 1024.f);
  float rs = rsqrtf(var + 1e-5f);
  #pragma unroll
  for (int c = 0; c < 4; ++c) {
    int col = threadIdx.x + c * 256;
    X[((size_t)b * 256 + p) * 1024 + col] = (v[c] - mu) * rs * gamma[col];
  }
}

// ---------------- CA kv (batched over layers): src bf16 [2048][sstride] -> per-(l,b) kv/kvT ----------------
__global__ __launch_bounds__(256) void kv_build_ca(const u16* __restrict__ src, int sstride, int scol,
                                                   const float* __restrict__ nul,
                                                   u16* __restrict__ kv, u16* __restrict__ kvT) {
  constexpr int JP = 160, J = 129;
  int b = blockIdx.x, l = blockIdx.y;
  for (int idx = threadIdx.x; idx < JP * 64; idx += 256) {
    int j = idx >> 6, d = idx & 63;
    u16 hv = 0;
    if (j == 0) hv = f2bf(nul[l * 64 + d]);
    else if (j < J) hv = src[(size_t)(b * 128 + j - 1) * sstride + l * scol + d];
    kv[(((size_t)l * 16 + b) * JP + j) * 64 + d] = hv;
    kvT[(((size_t)l * 16 + b) * 64 + d) * JP + j] = hv;
  }
}

// ---------------- MFMA attention (kv rows stride 64; kvT stride = JPT) ----------------
template<int NJT, int KSP, int JPT, bool CAUSAL, bool BIAS>
__global__ __launch_bounds__(256) void attn_mfma(const u16* __restrict__ Q, int QS,
                                                 const u16* __restrict__ kvb, const u16* __restrict__ kvTb,
                                                 const float* __restrict__ bias, u16* __restrict__ O, int J) {
  constexpr int PSTR = KSP * 32 + 16;
  __shared__ __align__(16) u16 Plds[4][16][PSTR];
  const int lane = threadIdx.x & 63, wave = threadIdx.x >> 6;
  const int h = blockIdx.y, b = blockIdx.z;
  const int i0 = blockIdx.x * 64 + wave * 16;
  const int c = lane & 15, g = lane >> 4;
  const float* biasrow = BIAS ? (bias + (size_t)h * 961) : nullptr;

  s16x8 aq[2];
  #pragma unroll
  for (int ks = 0; ks < 2; ++ks)
    aq[ks] = *(const s16x8*)(Q + (size_t)(b * 256 + i0 + c) * QS + h * 64 + ks * 32 + g * 8);

  f32x4 acc[NJT];
  #pragma unroll
  for (int jt = 0; jt < NJT; ++jt) acc[jt] = (f32x4){0.f, 0.f, 0.f, 0.f};

  const u16* kvB = kvb + (size_t)b * JPT * 64;
  __builtin_amdgcn_s_setprio(1);
  #pragma unroll
  for (int ks = 0; ks < 2; ++ks) {
    #pragma unroll
    for (int jt = 0; jt < NJT; ++jt) {
      s16x8 bf = *(const s16x8*)(kvB + (size_t)(jt * 16 + c) * 64 + ks * 32 + g * 8);
      acc[jt] = __builtin_amdgcn_mfma_f32_16x16x32_bf16(aq[ks], bf, acc[jt], 0, 0, 0);
    }
  }
  __builtin_amdgcn_s_setprio(0);

  const float NEGINF = -__builtin_inff();
  #pragma unroll
  for (int r = 0; r < 4; ++r) {
    const int i = i0 + g * 4 + r;
    float mx = NEGINF;
    #pragma unroll
    for (int jt = 0; jt < NJT; ++jt) {
      int j = jt * 16 + c;
      float s = acc[jt][r];
      if (j >= J) s = NEGINF;
      else {
        if (BIAS && j >= 1) {
          int t = j - 1;
          int idx = ((i >> 4) - (t >> 4) + 15) * 31 + ((i & 15) - (t & 15) + 15);
          s += biasrow[idx];
        }
        if (CAUSAL && j > i + 1) s = NEGINF;
      }
      acc[jt][r] = s;
      mx = fmaxf(mx, s);
    }
    #pragma unroll
    for (int o = 1; o < 16; o <<= 1) mx = fmaxf(mx, __shfl_xor(mx, o));
    float sum = 0.f;
    #pragma unroll
    for (int jt = 0; jt < NJT; ++jt) {
      float p = __expf(acc[jt][r] - mx);
      acc[jt][r] = p;
      sum += p;
    }
    #pragma unroll
    for (int o = 1; o < 16; o <<= 1) sum += __shfl_xor(sum, o);
    float inv = 1.f / sum;
    #pragma unroll
    for (int jt = 0; jt < NJT; ++jt)
      Plds[wave][g * 4 + r][jt * 16 + c] = f2bf(acc[jt][r] * inv);
  }
  #pragma unroll
  for (int z = 0; z < 4; ++z)
    Plds[wave][c][NJT * 16 + g * 4 + z] = 0;

  s16x8 pa[KSP];
  #pragma unroll
  for (int ks = 0; ks < KSP; ++ks)
    pa[ks] = *(const s16x8*)(&Plds[wave][c][ks * 32 + g * 8]);
  const u16* kvT = kvTb + (size_t)b * 64 * JPT;
  #pragma unroll
  for (int nt = 0; nt < 4; ++nt) {
    f32x4 ov = (f32x4){0.f, 0.f, 0.f, 0.f};
    __builtin_amdgcn_s_setprio(1);
    #pragma unroll
    for (int ks = 0; ks < KSP; ++ks) {
      s16x8 bv = *(const s16x8*)(kvT + (size_t)(nt * 16 + c) * JPT + ks * 32 + g * 8);
      ov = __builtin_amdgcn_mfma_f32_16x16x32_bf16(pa[ks], bv, ov, 0, 0, 0);
    }
    __builtin_amdgcn_s_setprio(0);
    #pragma unroll
    for (int r = 0; r < 4; ++r)
      O[(size_t)(b * 256 + i0 + g * 4 + r) * 1024 + h * 64 + nt * 16 + c] = f2bf(ov[r]);
  }
}

// =====================================================================
extern "C" void kernel_launch(void* const* d_in, const int* in_sizes, int n_in,
                              void* d_out, int out_size, void* d_ws, size_t ws_size,
                              hipStream_t stream) {
  const int*   ids     = (const int*)  d_in[0];
  const float* text    = (const float*)d_in[1];
  const float* tok     = (const float*)d_in[3];
  const float* hpos    = (const float*)d_in[4];
  const float* wpos    = (const float*)d_in[5];
  const float* start   = (const float*)d_in[6];
  const float* initg   = (const float*)d_in[7];
  const float* sa_g    = (const float*)d_in[8];
  const float* sa_Wq   = (const float*)d_in[9];
  const float* sa_nul  = (const float*)d_in[10];
  const float* sa_Wkv  = (const float*)d_in[11];
  const float* sa_Wout = (const float*)d_in[12];
  const float* sa_og   = (const float*)d_in[13];
  const float* sa_pb   = (const float*)d_in[14];
  const float* ca_g    = (const float*)d_in[15];
  const float* ca_Wq   = (const float*)d_in[16];
  const float* ca_nul  = (const float*)d_in[17];
  const float* ca_Wkv  = (const float*)d_in[18];
  const float* ca_Wout = (const float*)d_in[19];
  const float* ca_og   = (const float*)d_in[20];
  const float* ff_g1   = (const float*)d_in[21];
  const float* ff_W1   = (const float*)d_in[22];
  const float* ff_g2   = (const float*)d_in[23];
  const float* ff_W2   = (const float*)d_in[24];
  const float* fing    = (const float*)d_in[25];
  float* out = (float*)d_out;

  char* base = (char*)d_ws;
  size_t off = 0;
  auto carve = [&](size_t bytes) -> char* {
    off = (off + 255) & ~(size_t)255;
    char* p = base + off;
    off += bytes;
    return p;
  };
  float* x       = (float*)carve(4096ull * 1024 * 4);
  float* t       = (float*)carve(4096ull * 4096 * 4);   // aliased bf16 for all GEMM outs
  u16*   xn      = (u16*)  carve(4096ull * 1024 * 2);
  u16*   qkv     = (u16*)  carve(4096ull * 1152 * 2);
  u16*   qb      = (u16*)  carve(4096ull * 1024 * 2);
  u16*   ao      = (u16*)  carve(4096ull * 1024 * 2);
  u16*   hb      = (u16*)  carve(4096ull * 4096 * 2);
  u16*   kvbuf   = (u16*)  carve(16ull * 288 * 64 * 2);
  u16*   kvTbuf  = (u16*)  carve(16ull * 64 * 288 * 2);
  u16*   cakv    = (u16*)  carve(12ull * 16 * 160 * 64 * 2);
  u16*   cakvT   = (u16*)  carve(12ull * 16 * 64 * 160 * 2);
  u16*   catmp   = (u16*)  carve(2048ull * 768 * 2);
  u16*   cakvw   = (u16*)  carve(12ull * 64 * 768 * 2);
  u16*   cakvw1  = (u16*)  carve(128ull * 768 * 2);
  u16*   catmp1  = (u16*)  carve(2048ull * 128 * 2);
  u16*   textbf  = (u16*)  carve(2048ull * 768 * 2);
  u16*   tokbf   = (u16*)  carve(8192ull * 1024 * 2);
  float* biast   = (float*)carve(12ull * 16 * 961 * 4);
  u16*   tbb     = (u16*)t;   // bf16 view of t

  const size_t O_WQKV = 0;                    // [1152][1024]
  const size_t O_WOUT = 1179648;
  const size_t O_CWQ  = 2228224;
  const size_t O_CWOUT= 3276800;
  const size_t O_W1   = 4325376;
  const size_t O_W2   = 8519680;
  const size_t LAYER_E = 12713984ull;
  size_t off_now = (off + 255) & ~(size_t)255;
  bool allw = (off_now + 12 * LAYER_E * 2) <= ws_size;
  u16* wbase = (u16*)carve((allw ? 12 : 1) * LAYER_E * 2);

  dim3 tb8(32, 8);
  auto conv = [&](const float* in, u16* op, int R, int C, int L, float sc) {
    wconv_t<<<dim3(R / 32, C / 32, L), tb8, 0, stream>>>(in, op, R, C, (size_t)R * C, LAYER_E, sc);
  };
  if (allw) {
    conv(sa_Wq,   wbase + O_WQKV,            1024, 1024, 12, 0.125f);
    conv(sa_Wkv,  wbase + O_WQKV + 1048576,  1024, 64,   12, 1.f);
    zfill16<<<dim3(32, 12), 256, 0, stream>>>(wbase + O_WQKV + 1114112, LAYER_E);
    conv(sa_Wout, wbase + O_WOUT,  1024, 1024, 12, 1.f);
    conv(ca_Wq,   wbase + O_CWQ,   1024, 1024, 12, 0.125f);
    conv(ca_Wout, wbase + O_CWOUT, 1024, 1024, 12, 1.f);
    conv(ff_W1,   wbase + O_W1,    1024, 4096, 12, 1.f);
    conv(ff_W2,   wbase + O_W2,    4096, 1024, 12, 1.f);
    wconv_t<<<dim3(24, 2, 12), tb8, 0, stream>>>(ca_Wkv, cakvw, 768, 64, 49152, 49152, 1.f);
  }
  bias_tr<<<12, 256, 0, stream>>>(sa_pb, biast);
  // zero SA kv buffers once: pads (j>=257) stay zero; live region rewritten each layer
  zfill16<<<dim3(144, 1), 256, 0, stream>>>(kvbuf, 0);
  zfill16<<<dim3(144, 1), 256, 0, stream>>>(kvTbuf, 0);
  cvt_bf16_kernel<<<2048, 256, 0, stream>>>(tok, tokbf, 8192ull * 1024);
  cvt_bf16_kernel<<<1024, 256, 0, stream>>>(text, textbf, 2048ull * 768);
  if (allw) {
    gemm8<128, 128, 2, 4, true, false><<<dim3(16, 6, 1), 512, 0, stream>>>(textbf, cakvw, catmp, 2048, 768, 768, 768, nullptr, nullptr, nullptr);
    kv_build_ca<<<dim3(16, 12), 256, 0, stream>>>(catmp, 768, 64, ca_nul, cakv, cakvT);
  }
  embed_ln_kernel<<<dim3(256, 16), 256, 0, stream>>>(ids, tok, hpos, wpos, start, initg, x);
  ln1024<true><<<4096, 256, 0, stream>>>(x, sa_g, nullptr, xn);

  for (int l = 0; l < 12; ++l) {
    u16* W = allw ? (wbase + (size_t)l * LAYER_E) : wbase;
    if (!allw) {
      conv(sa_Wq   + (size_t)l * 1048576, W + O_WQKV,           1024, 1024, 1, 0.125f);
      conv(sa_Wkv  + (size_t)l * 65536,   W + O_WQKV + 1048576, 1024, 64,   1, 1.f);
      zfill16<<<dim3(32, 1), 256, 0, stream>>>(W + O_WQKV + 1114112, 0);
      conv(sa_Wout + (size_t)l * 1048576, W + O_WOUT,  1024, 1024, 1, 1.f);
      conv(ca_Wq   + (size_t)l * 1048576, W + O_CWQ,   1024, 1024, 1, 0.125f);
      conv(ca_Wout + (size_t)l * 1048576, W + O_CWOUT, 1024, 1024, 1, 1.f);
      conv(ff_W1   + (size_t)l * 4194304, W + O_W1,    1024, 4096, 1, 1.f);
      conv(ff_W2   + (size_t)l * 4194304, W + O_W2,    4096, 1024, 1, 1.f);
      wconv_t<<<dim3(24, 2, 1), tb8, 0, stream>>>(ca_Wkv + (size_t)l * 49152, cakvw1, 768, 64, 0, 0, 1.f);
      zfill16<<<dim3(24, 1), 256, 0, stream>>>(cakvw1 + 64 * 768, 0);
      gemm8<128, 128, 2, 4, true, false><<<dim3(16, 1, 1), 512, 0, stream>>>(textbf, cakvw1, catmp1, 2048, 128, 768, 768, nullptr, nullptr, nullptr);
      kv_build_ca<<<dim3(16, 1), 256, 0, stream>>>(catmp1, 128, 0, ca_nul + l * 64,
                                                   cakv + (size_t)l * 16 * 160 * 64,
                                                   cakvT + (size_t)l * 16 * 64 * 160);
    }
    // ---- self-attention block (xn holds LN(x)*sa_g[l]) ----
    gemm8<64, 128, 2, 4, true, true><<<dim3(64, 9, 1), 512, 0, stream>>>(xn, W + O_WQKV, qkv, 4096, 1152, 1024, 1024,
                                                                         sa_nul + l * 64, kvbuf, kvTbuf);
    attn_mfma<17, 9, 288, true, true><<<dim3(4, 16, 16), 256, 0, stream>>>(qkv, 1152, kvbuf, kvTbuf,
                                                                           biast + (size_t)l * 16 * 961, ao, 257);
    gemm8<64, 128, 2, 4, true, false><<<dim3(64, 8, 1), 512, 0, stream>>>(ao, W + O_WOUT, tbb, 4096, 1024, 1024, 1024, nullptr, nullptr, nullptr);
    lnln_kernel<<<4096, 256, 0, stream>>>(tbb, sa_og + l * 1024, x, ca_g + l * 1024, x, xn);
    // ---- cross-attention block ----
    gemm8<64, 128, 2, 4, true, false><<<dim3(64, 8, 1), 512, 0, stream>>>(xn, W + O_CWQ, qb, 4096, 1024, 1024, 1024, nullptr, nullptr, nullptr);
    attn_mfma<9, 5, 160, false, false><<<dim3(4, 16, 16), 256, 0, stream>>>(qb, 1024,
                                                                            cakv + (size_t)l * 16 * 160 * 64,
                                                                            cakvT + (size_t)l * 16 * 64 * 160,
                                                                            nullptr, ao, 129);
    gemm8<64, 128, 2, 4, true, false><<<dim3(64, 8, 1), 512, 0, stream>>>(ao, W + O_CWOUT, tbb, 4096, 1024, 1024, 1024, nullptr, nullptr, nullptr);
    lnln_kernel<<<4096, 256, 0, stream>>>(tbb, ca_og + l * 1024, x, ff_g1 + l * 1024, x, xn);
    // ---- feed-forward block (all bf16 intermediates) ----
    gemm8<256, 256, 2, 4, true, false><<<dim3(16, 16, 1), 512, 0, stream>>>(xn, W + O_W1, tbb, 4096, 4096, 1024, 1024, nullptr, nullptr, nullptr);
    gelu_ln_bf<<<4096, 256, 0, stream>>>(tbb, ff_g2 + (size_t)l * 4096, hb);
    gemm8<64, 128, 2, 4, true, false><<<dim3(64, 8, 1), 512, 0, stream>>>(hb, W + O_W2, tbb, 4096, 1024, 4096, 4096, nullptr, nullptr, nullptr);
    addln_kernel<<<4096, 256, 0, stream>>>(x, tbb, (l < 11 ? sa_g + (l + 1) * 1024 : fing), x, xn);
  }
  // ---- logits (xn = final LN) ----
  gemm8<256, 256, 2, 4, false, false><<<dim3(16, 32, 1), 512, 0, stream>>>(xn, tokbf, out, 4096, 8192, 1024, 1024, nullptr, nullptr, nullptr);
}